// Round 12
// baseline (139.578 us; speedup 1.0000x reference)
//
#include <hip/hip_runtime.h>
#include <hip/hip_bf16.h>
#include <math.h>

#define VOCAB 100000
#define INPUT_DIM 100
#define HIDDEN_DIM 10
#define BATCH 1024
#define SEQ 512

#define ROWS_PER_BLK 64
#define LDS_PITCH 102  // even -> 8B-aligned rows (ds_read_b64 ok);
                       // bank stride 6 -> 2 lanes/bank over wave64 = free

// ---------------------------------------------------------------------------
// Kernel A v4: proj[v][i] = dot(emb[v], W_ih[i]) + b_ih[i] + b_hh[i]
// r11 lessons: (a) W broadcasts from LDS = 3 extra ds_read per k-iter on the
// shared LDS pipe; (b) pitch 101 (odd) blocked ds_read vectorization.
// Fix: q = readfirstlane(wave id) -> W pointers provably uniform -> W/bias
// reads become s_load (scalar cache, no LDS/VALU cost). e rows at pitch 102
// -> compiler merges to ds_read_b64. Staging via float4 loads (7/thread).
// Inner loop: 50 ds_read_b64 + 300 v_fma(SGPR w) per thread.
// Launched TWICE this round (idempotent) for attribution: dur delta vs r11
// = 2*A_v4 - A_v3 regardless of harness floor; if slow it enters top-5
// with counters.
// ---------------------------------------------------------------------------
__global__ __launch_bounds__(256) void proj_kernel(
    const float* __restrict__ emb, const float* __restrict__ W_ih,
    const float* __restrict__ b_ih, const float* __restrict__ b_hh,
    float* __restrict__ proj) {
  __shared__ float se[ROWS_PER_BLK * LDS_PITCH];  // 26.1 KB

  const int t = threadIdx.x;
  const size_t base = (size_t)blockIdx.x * (ROWS_PER_BLK * INPUT_DIM);
  const size_t TOT = (size_t)VOCAB * INPUT_DIM;

  // Stage 64 rows (6400 floats = 1600 float4) with coalesced float4 loads.
#pragma unroll
  for (int l = 0; l < 7; ++l) {
    int n4 = t + 256 * l;       // float4 index
    if (n4 < 1600) {
      int n = n4 * 4;
      size_t g = base + n;
      float4 val;
      if (g + 3 < TOT) {
        val = *(const float4*)(emb + g);
      } else {
        val.x = (g + 0 < TOT) ? emb[g + 0] : 0.f;
        val.y = (g + 1 < TOT) ? emb[g + 1] : 0.f;
        val.z = (g + 2 < TOT) ? emb[g + 2] : 0.f;
        val.w = (g + 3 < TOT) ? emb[g + 3] : 0.f;
      }
      // scatter 4 elems (may straddle a row boundary)
      int r0 = n / 100, k0 = n - r0 * 100;
      se[r0 * LDS_PITCH + k0] = val.x;
      int n1 = n + 1; int r1 = n1 / 100, k1 = n1 - r1 * 100;
      se[r1 * LDS_PITCH + k1] = val.y;
      int n2 = n + 2; int r2 = n2 / 100, k2 = n2 - r2 * 100;
      se[r2 * LDS_PITCH + k2] = val.z;
      int n3 = n + 3; int r3 = n3 / 100, k3 = n3 - r3 * 100;
      se[r3 * LDS_PITCH + k3] = val.w;
    }
  }
  __syncthreads();

  const int row = t & 63;  // lane = emb row within block
  // Wave id forced uniform -> all W/bias addressing goes scalar path.
  const int q = __builtin_amdgcn_readfirstlane(threadIdx.x >> 6);
  const int v = blockIdx.x * ROWS_PER_BLK + row;
  const int iq2 = (q < 2) ? (q + 8) : q;  // dummy row for q>=2 (not stored)

  const float* W0 = W_ih + q * INPUT_DIM;        // uniform -> s_load
  const float* W1 = W_ih + (q + 4) * INPUT_DIM;  // uniform -> s_load
  const float* W2 = W_ih + iq2 * INPUT_DIM;      // uniform -> s_load

  float acc0 = b_ih[q] + b_hh[q];
  float acc1 = b_ih[q + 4] + b_hh[q + 4];
  float acc2 = b_ih[iq2] + b_hh[iq2];

  const float* er = se + row * LDS_PITCH;
#pragma unroll
  for (int k = 0; k < INPUT_DIM; ++k) {
    float e = er[k];  // per-lane LDS, b64-mergeable, conflict-free
    acc0 = fmaf(e, W0[k], acc0);
    acc1 = fmaf(e, W1[k], acc1);
    acc2 = fmaf(e, W2[k], acc2);
  }

  if (v < VOCAB) {
    float* pv = proj + (size_t)v * HIDDEN_DIM;
    pv[q] = acc0;
    pv[q + 4] = acc1;
    if (q < 2) pv[q + 8] = acc2;
  }
}

// ---------------------------------------------------------------------------
// Kernel B: the 512-step recurrence. One WAVE per batch element (1024 waves
// = 1/SIMD chip-wide). Lane i<10 owns h[i]; h[j] broadcast via v_readlane.
// x indices staged into LDS once per wave; per-phase index reads on LGKM
// counter so the VM queue carries only proj gathers (3 phases in flight).
// UNCHANGED from rounds 8-11 for clean attribution of the kernel-A fix.
// ---------------------------------------------------------------------------
__global__ __launch_bounds__(256, 1) void scan_kernel(
    const int* __restrict__ x, const float* __restrict__ proj,
    const float* __restrict__ W_hh, const float* __restrict__ W_fc,
    const float* __restrict__ b_fc, float* __restrict__ out) {
  __shared__ int sIdx[4][SEQ];  // 8 KB: per-wave index row

  int lane = threadIdx.x & 63;
  int widx = threadIdx.x >> 6;  // wave within block, 0..3
  int b = __builtin_amdgcn_readfirstlane((int)(blockIdx.x * 4 + widx));
  int i = (lane < HIDDEN_DIM) ? lane : 0;  // idle lanes shadow row 0

  float Wr[HIDDEN_DIM];
#pragma unroll
  for (int j = 0; j < HIDDEN_DIM; ++j) Wr[j] = W_hh[i * HIDDEN_DIM + j];
  float wfc = (lane < HIDDEN_DIM) ? W_fc[lane] : 0.f;

  // Stage this wave's 512 indices into LDS (coalesced, once).
  const int4* xb4 = (const int4*)(x + (size_t)b * SEQ);
  int4* s4 = (int4*)(sIdx[widx]);
  s4[lane] = xb4[lane];            // ints 0..255
  s4[64 + lane] = xb4[64 + lane];  // ints 256..511
  // No barrier needed: each wave reads only LDS it wrote itself.

  const float* projLane = proj + i;  // per-lane base
  float h = 0.f;

#define LOADIDX(Q0, Q1, base)                              \
  {                                                        \
    int bc_ = (base) <= (SEQ - 8) ? (base) : (SEQ - 8);    \
    Q0 = s4[bc_ >> 2];                                     \
    Q1 = s4[(bc_ >> 2) + 1];                               \
  }
#define GATHER(P, Q0, Q1)                                  \
  P[0] = projLane[(unsigned)Q0.x * 10u];                   \
  P[1] = projLane[(unsigned)Q0.y * 10u];                   \
  P[2] = projLane[(unsigned)Q0.z * 10u];                   \
  P[3] = projLane[(unsigned)Q0.w * 10u];                   \
  P[4] = projLane[(unsigned)Q1.x * 10u];                   \
  P[5] = projLane[(unsigned)Q1.y * 10u];                   \
  P[6] = projLane[(unsigned)Q1.z * 10u];                   \
  P[7] = projLane[(unsigned)Q1.w * 10u];
#define COMPUTE(P)                                         \
  _Pragma("unroll") for (int u = 0; u < 8; ++u) {          \
    float hj[HIDDEN_DIM];                                  \
    _Pragma("unroll") for (int j = 0; j < HIDDEN_DIM; ++j) \
      hj[j] = __uint_as_float(                             \
          __builtin_amdgcn_readlane(__float_as_uint(h), j)); \
    float a0 = fmaf(Wr[0], hj[0], P[u]);                   \
    float a1 = Wr[1] * hj[1];                              \
    a0 = fmaf(Wr[2], hj[2], a0);                           \
    a1 = fmaf(Wr[3], hj[3], a1);                           \
    a0 = fmaf(Wr[4], hj[4], a0);                           \
    a1 = fmaf(Wr[5], hj[5], a1);                           \
    a0 = fmaf(Wr[6], hj[6], a0);                           \
    a1 = fmaf(Wr[7], hj[7], a1);                           \
    a0 = fmaf(Wr[8], hj[8], a0);                           \
    a1 = fmaf(Wr[9], hj[9], a1);                           \
    h = fmaxf(a0 + a1, 0.f);                               \
  }

  int4 Ia0, Ia1, Ib0, Ib1, Ic0, Ic1, Id0, Id1;
  float pA[8], pB[8], pC[8], pD[8];

  LOADIDX(Ia0, Ia1, 0) LOADIDX(Ib0, Ib1, 8) LOADIDX(Ic0, Ic1, 16)
  GATHER(pA, Ia0, Ia1) GATHER(pB, Ib0, Ib1) GATHER(pC, Ic0, Ic1)
  LOADIDX(Id0, Id1, 24)

  for (int tt = 0; tt < SEQ; tt += 32) {
    GATHER(pD, Id0, Id1) LOADIDX(Ia0, Ia1, tt + 32) COMPUTE(pA)
    GATHER(pA, Ia0, Ia1) LOADIDX(Ib0, Ib1, tt + 40) COMPUTE(pB)
    GATHER(pB, Ib0, Ib1) LOADIDX(Ic0, Ic1, tt + 48) COMPUTE(pC)
    GATHER(pC, Ic0, Ic1) LOADIDX(Id0, Id1, tt + 56) COMPUTE(pD)
  }
#undef LOADIDX
#undef GATHER
#undef COMPUTE

  // FC + sigmoid over lanes 0..9.
  float prod = wfc * h;
  float z = 0.f;
#pragma unroll
  for (int j = 0; j < HIDDEN_DIM; ++j)
    z += __uint_as_float(__builtin_amdgcn_readlane(__float_as_uint(prod), j));
  if (lane == 0) out[b] = 1.f / (1.f + expf(-(z + b_fc[0])));
}

extern "C" void kernel_launch(void* const* d_in, const int* in_sizes, int n_in,
                              void* d_out, int out_size, void* d_ws, size_t ws_size,
                              hipStream_t stream) {
  const int*   x    = (const int*)d_in[0];
  const float* emb  = (const float*)d_in[1];
  const float* W_ih = (const float*)d_in[2];
  const float* b_ih = (const float*)d_in[3];
  const float* W_hh = (const float*)d_in[4];
  const float* b_hh = (const float*)d_in[5];
  const float* W_fc = (const float*)d_in[6];
  const float* b_fc = (const float*)d_in[7];
  float* out = (float*)d_out;

  float* proj = (float*)d_ws;  // VOCAB*HIDDEN_DIM*4 = 4 MB scratch

  int blocksA = (VOCAB + ROWS_PER_BLK - 1) / ROWS_PER_BLK;  // 1563
  // DIAGNOSTIC double-launch (idempotent; same work every call).
  // dur_r12 - dur_r11 = 2*A_v4 - A_v3 independent of the harness floor;
  // a slow A_v4 lands in top-5 WITH counters. Revert to single next round.
  proj_kernel<<<blocksA, 256, 0, stream>>>(emb, W_ih, b_ih, b_hh, proj);
  proj_kernel<<<blocksA, 256, 0, stream>>>(emb, W_ih, b_ih, b_hh, proj);

  int blocksB = BATCH / 4;  // 4 waves/block, one wave per batch element
  scan_kernel<<<blocksB, 256, 0, stream>>>(x, proj, W_hh, W_fc, b_fc, out);
}

// Round 14
// 138.001 us; speedup vs baseline: 1.0114x; 1.0114x over previous
//
#include <hip/hip_runtime.h>
#include <hip/hip_bf16.h>
#include <math.h>

#define VOCAB 100000
#define INPUT_DIM 100
#define HIDDEN_DIM 10
#define BATCH 1024
#define SEQ 512

#define ROWS_PER_BLK 64
#define LDS_PITCH 102  // even -> 8B-aligned rows; stride 6 banks -> free

// ---------------------------------------------------------------------------
// Kernel A v4 (unchanged): proj[v][i] = dot(emb[v], W_ih[i]) + b_ih + b_hh.
// Staging via float4; W/bias on the scalar path (readfirstlane'd wave id);
// per-lane e rows from LDS at even pitch (ds_read_b64-mergeable).
// Measured ~14-20 us via r12 double-launch delta.
// ---------------------------------------------------------------------------
__global__ __launch_bounds__(256) void proj_kernel(
    const float* __restrict__ emb, const float* __restrict__ W_ih,
    const float* __restrict__ b_ih, const float* __restrict__ b_hh,
    float* __restrict__ proj) {
  __shared__ float se[ROWS_PER_BLK * LDS_PITCH];  // 26.1 KB

  const int t = threadIdx.x;
  const size_t base = (size_t)blockIdx.x * (ROWS_PER_BLK * INPUT_DIM);
  const size_t TOT = (size_t)VOCAB * INPUT_DIM;

#pragma unroll
  for (int l = 0; l < 7; ++l) {
    int n4 = t + 256 * l;
    if (n4 < 1600) {
      int n = n4 * 4;
      size_t g = base + n;
      float4 val;
      if (g + 3 < TOT) {
        val = *(const float4*)(emb + g);
      } else {
        val.x = (g + 0 < TOT) ? emb[g + 0] : 0.f;
        val.y = (g + 1 < TOT) ? emb[g + 1] : 0.f;
        val.z = (g + 2 < TOT) ? emb[g + 2] : 0.f;
        val.w = (g + 3 < TOT) ? emb[g + 3] : 0.f;
      }
      int r0 = n / 100, k0 = n - r0 * 100;
      se[r0 * LDS_PITCH + k0] = val.x;
      int n1 = n + 1; int r1 = n1 / 100, k1 = n1 - r1 * 100;
      se[r1 * LDS_PITCH + k1] = val.y;
      int n2 = n + 2; int r2 = n2 / 100, k2 = n2 - r2 * 100;
      se[r2 * LDS_PITCH + k2] = val.z;
      int n3 = n + 3; int r3 = n3 / 100, k3 = n3 - r3 * 100;
      se[r3 * LDS_PITCH + k3] = val.w;
    }
  }
  __syncthreads();

  const int row = t & 63;
  const int q = __builtin_amdgcn_readfirstlane(threadIdx.x >> 6);
  const int v = blockIdx.x * ROWS_PER_BLK + row;
  const int iq2 = (q < 2) ? (q + 8) : q;

  const float* W0 = W_ih + q * INPUT_DIM;
  const float* W1 = W_ih + (q + 4) * INPUT_DIM;
  const float* W2 = W_ih + iq2 * INPUT_DIM;

  float acc0 = b_ih[q] + b_hh[q];
  float acc1 = b_ih[q + 4] + b_hh[q + 4];
  float acc2 = b_ih[iq2] + b_hh[iq2];

  const float* er = se + row * LDS_PITCH;
#pragma unroll
  for (int k = 0; k < INPUT_DIM; ++k) {
    float e = er[k];
    acc0 = fmaf(e, W0[k], acc0);
    acc1 = fmaf(e, W1[k], acc1);
    acc2 = fmaf(e, W2[k], acc2);
  }

  if (v < VOCAB) {
    float* pv = proj + (size_t)v * HIDDEN_DIM;
    pv[q] = acc0;
    pv[q + 4] = acc1;
    if (q < 2) pv[q + 8] = acc2;
  }
}

// ---------------------------------------------------------------------------
// Kernel B v2: producer/consumer wave split.
// r12 lesson: VGPR_Count=44 proves the compiler collapsed the 4-phase
// register pipeline and serializes vmcnt waits -> source-level pipelining
// can't win (the compiler owns the waitcnts). Structural fix: the consumer
// wave executes ZERO vector-memory instructions in the hot loop.
//   block = 1 batch element, 128 threads = 2 waves.
//   wave1 (producer): gathers chunk c+1's 32 proj rows (float2 gathers,
//     5 lanes/row) into an LDS ring slot. ~500 cyc/chunk incl. L2 latency,
//     hidden under the consumer's ~1660 cyc/chunk.
//   wave0 (consumer): per step ONE ds_read_b32 (imm offset) + 10 readlane
//     + 10 FMA + max. No vmem -> no vmcnt stalls possible.
//   __syncthreads() once per 32-step chunk (double-buffered ring).
// ---------------------------------------------------------------------------
#define CHUNK 32
#define NCHUNK (SEQ / CHUNK)  // 16
#define RPITCH 12             // even (8B-aligned float2 writes)

__global__ __launch_bounds__(128, 1) void scan_kernel(
    const int* __restrict__ x, const float* __restrict__ proj,
    const float* __restrict__ W_hh, const float* __restrict__ W_fc,
    const float* __restrict__ b_fc, float* __restrict__ out) {
  __shared__ int sIdx[SEQ];                  // 2 KB
  __shared__ float ring[2][CHUNK * RPITCH];  // 3 KB

  const int t = threadIdx.x;
  const int lane = t & 63;
  const int widx = t >> 6;  // 0 = consumer wave, 1 = producer wave
  const int b = blockIdx.x;

  // Stage x: 128 threads x int4 = exactly 512 ints, coalesced.
  ((int4*)sIdx)[t] = ((const int4*)(x + (size_t)b * SEQ))[t];
  __syncthreads();

  const int i = (lane < HIDDEN_DIM) ? lane : 0;

  // Consumer-only state (wave-uniform branch).
  float Wr[HIDDEN_DIM];
  float wfc = 0.f;
  if (widx == 0) {
#pragma unroll
    for (int j = 0; j < HIDDEN_DIM; ++j) Wr[j] = W_hh[i * HIDDEN_DIM + j];
    wfc = (lane < HIDDEN_DIM) ? W_fc[lane] : 0.f;
  }

  // Producer: fill ring slot (src&1) with chunk src's 32 proj rows.
  // 32 rows x 5 float2 = 160 parts; j = pass*64 + lane; 5 lanes share a row.
#define FILL(src)                                                   \
  {                                                                 \
    const int rbase_ = (src) * CHUNK;                               \
    float* dst_ = ring[(src) & 1];                                  \
    _Pragma("unroll") for (int pass = 0; pass < 3; ++pass) {        \
      int j_ = pass * 64 + lane;                                    \
      if (j_ < CHUNK * 5) {                                         \
        int r_ = j_ / 5;                                            \
        int p_ = j_ - r_ * 5;                                       \
        int idx_ = sIdx[rbase_ + r_];                               \
        float2 val_ =                                               \
            *(const float2*)(proj + (size_t)idx_ * 10u + p_ * 2);   \
        *(float2*)(dst_ + r_ * RPITCH + p_ * 2) = val_;             \
      }                                                             \
    }                                                               \
  }

  if (widx == 1) FILL(0);
  __syncthreads();

  float h = 0.f;
  for (int c = 0; c < NCHUNK; ++c) {
    if (widx == 1) {
      if (c + 1 < NCHUNK) FILL(c + 1);
    } else {
      const float* rg = ring[c & 1] + i;  // VGPR base + imm offsets below
#pragma unroll
      for (int tt = 0; tt < CHUNK; ++tt) {
        float pt = rg[tt * RPITCH];  // ds_read_b32 offset:tt*48
        float hj[HIDDEN_DIM];
#pragma unroll
        for (int j = 0; j < HIDDEN_DIM; ++j)
          hj[j] = __uint_as_float(
              __builtin_amdgcn_readlane(__float_as_uint(h), j));
        float a0 = fmaf(Wr[0], hj[0], pt);
        float a1 = Wr[1] * hj[1];
        a0 = fmaf(Wr[2], hj[2], a0);
        a1 = fmaf(Wr[3], hj[3], a1);
        a0 = fmaf(Wr[4], hj[4], a0);
        a1 = fmaf(Wr[5], hj[5], a1);
        a0 = fmaf(Wr[6], hj[6], a0);
        a1 = fmaf(Wr[7], hj[7], a1);
        a0 = fmaf(Wr[8], hj[8], a0);
        a1 = fmaf(Wr[9], hj[9], a1);
        h = fmaxf(a0 + a1, 0.f);
      }
    }
    __syncthreads();
  }
#undef FILL

  // FC + sigmoid (consumer wave only).
  if (widx == 0) {
    float prod = wfc * h;
    float z = 0.f;
#pragma unroll
    for (int j = 0; j < HIDDEN_DIM; ++j)
      z += __uint_as_float(__builtin_amdgcn_readlane(__float_as_uint(prod), j));
    if (lane == 0) out[b] = 1.f / (1.f + expf(-(z + b_fc[0])));
  }
}

extern "C" void kernel_launch(void* const* d_in, const int* in_sizes, int n_in,
                              void* d_out, int out_size, void* d_ws, size_t ws_size,
                              hipStream_t stream) {
  const int*   x    = (const int*)d_in[0];
  const float* emb  = (const float*)d_in[1];
  const float* W_ih = (const float*)d_in[2];
  const float* b_ih = (const float*)d_in[3];
  const float* W_hh = (const float*)d_in[4];
  const float* b_hh = (const float*)d_in[5];
  const float* W_fc = (const float*)d_in[6];
  const float* b_fc = (const float*)d_in[7];
  float* out = (float*)d_out;

  float* proj = (float*)d_ws;  // VOCAB*HIDDEN_DIM*4 = 4 MB scratch

  int blocksA = (VOCAB + ROWS_PER_BLK - 1) / ROWS_PER_BLK;  // 1563
  proj_kernel<<<blocksA, 256, 0, stream>>>(emb, W_ih, b_ih, b_hh, proj);

  // One block (2 waves: producer + consumer) per batch element.
  scan_kernel<<<BATCH, 128, 0, stream>>>(x, proj, W_hh, W_fc, b_fc, out);
}